// Round 1
// baseline (676.604 us; speedup 1.0000x reference)
//
#include <hip/hip_runtime.h>
#include <hip/hip_bf16.h>

#define N_NODES 100000
#define N_EDGES 500000
#define H 128
#define EPS 1e-5f

typedef __attribute__((ext_vector_type(8))) short bf16x8;
typedef __attribute__((ext_vector_type(4))) float f32x4;

__device__ __forceinline__ unsigned short f2bf(float f) {
  unsigned int u = __builtin_bit_cast(unsigned int, f);
  u += 0x7FFFu + ((u >> 16) & 1u);
  return (unsigned short)(u >> 16);
}

// XOR-swizzled LDS layout for a 128x128 bf16 tile (linear 32KB, conflict-free
// ds_read_b128 when 16 consecutive rows are read at the same k0).
// element (r,k) -> ushort index r*128 + (k ^ ((r&7)<<3)); 16B chunks stay intact.
__device__ __forceinline__ int swz(int r, int k) {
  return r * 128 + (k ^ ((r & 7) << 3));
}

union PK8 { unsigned short u[8]; uint4 q; };

// Stage one 64-float half-row (f32 global -> bf16 LDS). src==nullptr -> zeros.
__device__ __forceinline__ void stage_a_half(unsigned short* Abuf, int r, int k0,
                                             const float* src) {
  #pragma unroll
  for (int j = 0; j < 8; ++j) {
    PK8 pk;
    if (src) {
      float4 v0 = *(const float4*)(src + j * 8);
      float4 v1 = *(const float4*)(src + j * 8 + 4);
      pk.u[0] = f2bf(v0.x); pk.u[1] = f2bf(v0.y);
      pk.u[2] = f2bf(v0.z); pk.u[3] = f2bf(v0.w);
      pk.u[4] = f2bf(v1.x); pk.u[5] = f2bf(v1.y);
      pk.u[6] = f2bf(v1.z); pk.u[7] = f2bf(v1.w);
    } else {
      #pragma unroll
      for (int q = 0; q < 8; ++q) pk.u[q] = 0;
    }
    *(uint4*)&Abuf[swz(r, k0 + j * 8)] = pk.q;
  }
}

// Stage a 128x128 f32 weight block transposed into LDS: Wbuf[n][k] = W[k][n], bf16.
__device__ __forceinline__ void stage_w(unsigned short* Wbuf, const float* Wsrc) {
  const int t = threadIdx.x;
  const int k = t >> 1;
  const int n0 = (t & 1) * 64;
  const float* src = Wsrc + (long)k * H + n0;
  #pragma unroll
  for (int j = 0; j < 16; ++j) {
    float4 v = *(const float4*)(src + j * 4);
    const int n = n0 + j * 4;
    Wbuf[swz(n + 0, k)] = f2bf(v.x);
    Wbuf[swz(n + 1, k)] = f2bf(v.y);
    Wbuf[swz(n + 2, k)] = f2bf(v.z);
    Wbuf[swz(n + 3, k)] = f2bf(v.w);
  }
}

// [32 x 128] += A[32 x 128] @ B[128 x 128]; wave-tile = 2 row-tiles x 8 col-tiles.
__device__ __forceinline__ void gemm128(const unsigned short* Abuf,
                                        const unsigned short* Wbuf,
                                        int row_base, int m0, int kq,
                                        f32x4 acc[2][8]) {
  #pragma unroll
  for (int kk = 0; kk < 4; ++kk) {
    const int k0 = kk * 32 + kq * 8;
    bf16x8 a0 = *(const bf16x8*)&Abuf[swz(row_base + m0, k0)];
    bf16x8 a1 = *(const bf16x8*)&Abuf[swz(row_base + 16 + m0, k0)];
    #pragma unroll
    for (int tc = 0; tc < 8; ++tc) {
      bf16x8 b = *(const bf16x8*)&Wbuf[swz(tc * 16 + m0, k0)];
      acc[0][tc] = __builtin_amdgcn_mfma_f32_16x16x32_bf16(a0, b, acc[0][tc], 0, 0, 0);
      acc[1][tc] = __builtin_amdgcn_mfma_f32_16x16x32_bf16(a1, b, acc[1][tc], 0, 0, 0);
    }
  }
}

// C-layout: col = tc*16 + (lane&15), row = tr*16 + (lane>>4)*4 + i  (m89-verified)
__device__ __forceinline__ void write_hidden_relu(unsigned short* Abuf, f32x4 acc[2][8],
                                                  const float* __restrict__ bias,
                                                  int row_base, int m0, int kq) {
  #pragma unroll
  for (int tc = 0; tc < 8; ++tc) {
    const int col = tc * 16 + m0;
    const float b = bias[col];
    #pragma unroll
    for (int tr = 0; tr < 2; ++tr)
      #pragma unroll
      for (int i = 0; i < 4; ++i)
        Abuf[swz(row_base + tr * 16 + kq * 4 + i, col)] =
            f2bf(fmaxf(acc[tr][tc][i] + b, 0.0f));
  }
}

__device__ __forceinline__ void zero_acc(f32x4 acc[2][8]) {
  #pragma unroll
  for (int a = 0; a < 2; ++a)
    #pragma unroll
    for (int b = 0; b < 8; ++b)
      acc[a][b] = (f32x4){0.f, 0.f, 0.f, 0.f};
}

// LayerNorm stats per row: mean + rsqrt(var+eps). Row spread over 16 lanes
// (same kq group) x 8 col-tiles; butterfly reduce over lane&15.
__device__ __forceinline__ void ln_stats(const f32x4 acc[2][8], float mu[2][4],
                                         float rv[2][4]) {
  #pragma unroll
  for (int tr = 0; tr < 2; ++tr) {
    float s[4] = {0, 0, 0, 0}, ss[4] = {0, 0, 0, 0};
    #pragma unroll
    for (int tc = 0; tc < 8; ++tc)
      #pragma unroll
      for (int i = 0; i < 4; ++i) {
        const float v = acc[tr][tc][i];
        s[i] += v;
        ss[i] += v * v;
      }
    #pragma unroll
    for (int off = 1; off < 16; off <<= 1) {
      #pragma unroll
      for (int i = 0; i < 4; ++i) {
        s[i] += __shfl_xor(s[i], off);
        ss[i] += __shfl_xor(ss[i], off);
      }
    }
    #pragma unroll
    for (int i = 0; i < 4; ++i) {
      const float m = s[i] * (1.0f / 128.0f);
      const float var = ss[i] * (1.0f / 128.0f) - m * m;
      mu[tr][i] = m;
      rv[tr][i] = rsqrtf(var + EPS);
    }
  }
}

__global__ __launch_bounds__(256, 2) void edge_kernel(
    const float* __restrict__ x, const float* __restrict__ edge_attr,
    const int* __restrict__ eidx,
    const float* __restrict__ eW1, const float* __restrict__ eb1,
    const float* __restrict__ eW2, const float* __restrict__ eb2,
    const float* __restrict__ eW3, const float* __restrict__ eb3,
    const float* __restrict__ eg, const float* __restrict__ ebeta,
    float* __restrict__ out_e, float* __restrict__ agg) {
  __shared__ unsigned short Abuf[128 * 128];
  __shared__ unsigned short Wbuf[128 * 128];

  const int t = threadIdx.x;
  const int lane = t & 63;
  const int wave = t >> 6;
  const int row_base = wave * 32;
  const int m0 = lane & 15;
  const int kq = lane >> 4;
  const long e0 = (long)blockIdx.x * 128;
  const int* sidx = eidx;
  const int* ridx = eidx + N_EDGES;

  // staging map: thread -> (row, 64-col half)
  const int sr = t >> 1;
  const int sk0 = (t & 1) * 64;
  const long se = e0 + sr;
  const bool svalid = (se < N_EDGES);

  f32x4 acc[2][8];
  zero_acc(acc);

  // ---- Layer 1: three K=128 sub-GEMMs: x[s]@W1a + x[r]@W1b + ea@W1c ----
  for (int p = 0; p < 3; ++p) {
    __syncthreads();
    const float* src = nullptr;
    if (svalid) {
      if (p == 0)      src = x + (long)sidx[se] * H + sk0;
      else if (p == 1) src = x + (long)ridx[se] * H + sk0;
      else             src = edge_attr + se * (long)H + sk0;
    }
    stage_a_half(Abuf, sr, sk0, src);
    stage_w(Wbuf, eW1 + (long)p * 128 * H);
    __syncthreads();
    gemm128(Abuf, Wbuf, row_base, m0, kq, acc);
  }

  // ---- Layer 2 ----
  __syncthreads();
  write_hidden_relu(Abuf, acc, eb1, row_base, m0, kq);
  stage_w(Wbuf, eW2);
  zero_acc(acc);
  __syncthreads();
  gemm128(Abuf, Wbuf, row_base, m0, kq, acc);

  // ---- Layer 3 ----
  __syncthreads();
  write_hidden_relu(Abuf, acc, eb2, row_base, m0, kq);
  stage_w(Wbuf, eW3);
  zero_acc(acc);
  __syncthreads();
  gemm128(Abuf, Wbuf, row_base, m0, kq, acc);

  // ---- Epilogue: +b3, LayerNorm, residual write, atomic scatter ----
  float gm[8], bt[8];
  #pragma unroll
  for (int tc = 0; tc < 8; ++tc) {
    const int col = tc * 16 + m0;
    const float b3 = eb3[col];
    gm[tc] = eg[col];
    bt[tc] = ebeta[col];
    #pragma unroll
    for (int tr = 0; tr < 2; ++tr)
      #pragma unroll
      for (int i = 0; i < 4; ++i)
        acc[tr][tc][i] += b3;
  }
  float mu[2][4], rv[2][4];
  ln_stats(acc, mu, rv);

  #pragma unroll
  for (int tr = 0; tr < 2; ++tr)
    #pragma unroll
    for (int i = 0; i < 4; ++i) {
      const int row = row_base + tr * 16 + kq * 4 + i;
      const long e = e0 + row;
      if (e < N_EDGES) {
        const int rcv = ridx[e];
        const float m_ = mu[tr][i], r_ = rv[tr][i];
        const float* ea = edge_attr + e * (long)H;
        float* oe = out_e + e * (long)H;
        float* ag = agg + (long)rcv * H;
        #pragma unroll
        for (int tc = 0; tc < 8; ++tc) {
          const int col = tc * 16 + m0;
          const float y = (acc[tr][tc][i] - m_) * r_ * gm[tc] + bt[tc];
          oe[col] = ea[col] + y;
          atomicAdd(&ag[col], y);
        }
      }
    }
}

__global__ __launch_bounds__(256, 2) void node_kernel(
    const float* __restrict__ x, const float* __restrict__ agg,
    const float* __restrict__ nW1, const float* __restrict__ nb1,
    const float* __restrict__ nW2, const float* __restrict__ nb2,
    const float* __restrict__ nW3, const float* __restrict__ nb3,
    const float* __restrict__ ng, const float* __restrict__ nbeta,
    float* __restrict__ out_x) {
  __shared__ unsigned short Abuf[128 * 128];
  __shared__ unsigned short Wbuf[128 * 128];

  const int t = threadIdx.x;
  const int lane = t & 63;
  const int wave = t >> 6;
  const int row_base = wave * 32;
  const int m0 = lane & 15;
  const int kq = lane >> 4;
  const long n0 = (long)blockIdx.x * 128;

  const int sr = t >> 1;
  const int sk0 = (t & 1) * 64;
  const long sn = n0 + sr;
  const bool svalid = (sn < N_NODES);

  f32x4 acc[2][8];
  zero_acc(acc);

  // ---- Layer 1: x@W1a + agg@W1b ----
  for (int p = 0; p < 2; ++p) {
    __syncthreads();
    const float* src = nullptr;
    if (svalid) src = (p == 0 ? x : agg) + sn * (long)H + sk0;
    stage_a_half(Abuf, sr, sk0, src);
    stage_w(Wbuf, nW1 + (long)p * 128 * H);
    __syncthreads();
    gemm128(Abuf, Wbuf, row_base, m0, kq, acc);
  }

  // ---- Layer 2 ----
  __syncthreads();
  write_hidden_relu(Abuf, acc, nb1, row_base, m0, kq);
  stage_w(Wbuf, nW2);
  zero_acc(acc);
  __syncthreads();
  gemm128(Abuf, Wbuf, row_base, m0, kq, acc);

  // ---- Layer 3 ----
  __syncthreads();
  write_hidden_relu(Abuf, acc, nb2, row_base, m0, kq);
  stage_w(Wbuf, nW3);
  zero_acc(acc);
  __syncthreads();
  gemm128(Abuf, Wbuf, row_base, m0, kq, acc);

  // ---- Epilogue: +b3, LayerNorm, residual, store ----
  float gm[8], bt[8];
  #pragma unroll
  for (int tc = 0; tc < 8; ++tc) {
    const int col = tc * 16 + m0;
    const float b3 = nb3[col];
    gm[tc] = ng[col];
    bt[tc] = nbeta[col];
    #pragma unroll
    for (int tr = 0; tr < 2; ++tr)
      #pragma unroll
      for (int i = 0; i < 4; ++i)
        acc[tr][tc][i] += b3;
  }
  float mu[2][4], rv[2][4];
  ln_stats(acc, mu, rv);

  #pragma unroll
  for (int tr = 0; tr < 2; ++tr)
    #pragma unroll
    for (int i = 0; i < 4; ++i) {
      const int row = row_base + tr * 16 + kq * 4 + i;
      const long n = n0 + row;
      if (n < N_NODES) {
        const float m_ = mu[tr][i], r_ = rv[tr][i];
        const float* xr = x + n * (long)H;
        float* ox = out_x + n * (long)H;
        #pragma unroll
        for (int tc = 0; tc < 8; ++tc) {
          const int col = tc * 16 + m0;
          const float y = (acc[tr][tc][i] - m_) * r_ * gm[tc] + bt[tc];
          ox[col] = xr[col] + y;
        }
      }
    }
}

extern "C" void kernel_launch(void* const* d_in, const int* in_sizes, int n_in,
                              void* d_out, int out_size, void* d_ws, size_t ws_size,
                              hipStream_t stream) {
  (void)in_sizes; (void)n_in; (void)out_size; (void)ws_size;
  const float* x         = (const float*)d_in[0];
  const float* edge_attr = (const float*)d_in[1];
  const int*   eidx      = (const int*)d_in[2];
  const float* eW1 = (const float*)d_in[3];
  const float* eb1 = (const float*)d_in[4];
  const float* eW2 = (const float*)d_in[5];
  const float* eb2 = (const float*)d_in[6];
  const float* eW3 = (const float*)d_in[7];
  const float* eb3 = (const float*)d_in[8];
  const float* eg  = (const float*)d_in[9];
  const float* ebt = (const float*)d_in[10];
  const float* nW1 = (const float*)d_in[11];
  const float* nb1 = (const float*)d_in[12];
  const float* nW2 = (const float*)d_in[13];
  const float* nb2 = (const float*)d_in[14];
  const float* nW3 = (const float*)d_in[15];
  const float* nb3 = (const float*)d_in[16];
  const float* ng  = (const float*)d_in[17];
  const float* nbt = (const float*)d_in[18];

  float* out_x = (float*)d_out;                     // N_NODES*H
  float* out_e = (float*)d_out + (size_t)N_NODES * H;  // N_EDGES*H
  float* agg   = (float*)d_ws;                      // N_NODES*H scratch

  hipMemsetAsync(agg, 0, (size_t)N_NODES * H * sizeof(float), stream);

  const int eblocks = (N_EDGES + 127) / 128;  // 3907
  const int nblocks = (N_NODES + 127) / 128;  // 782
  edge_kernel<<<eblocks, 256, 0, stream>>>(x, edge_attr, eidx, eW1, eb1, eW2, eb2,
                                           eW3, eb3, eg, ebt, out_e, agg);
  node_kernel<<<nblocks, 256, 0, stream>>>(x, agg, nW1, nb1, nW2, nb2, nW3, nb3,
                                           ng, nbt, out_x);
}

// Round 2
// 447.442 us; speedup vs baseline: 1.5122x; 1.5122x over previous
//
#include <hip/hip_runtime.h>
#include <hip/hip_bf16.h>

#define N_NODES 100000
#define N_EDGES 500000
#define H 128
#define EPS 1e-5f

typedef __attribute__((ext_vector_type(8))) short bf16x8;
typedef __attribute__((ext_vector_type(4))) float f32x4;

__device__ __forceinline__ unsigned short f2bf(float f) {
  unsigned int u = __builtin_bit_cast(unsigned int, f);
  u += 0x7FFFu + ((u >> 16) & 1u);
  return (unsigned short)(u >> 16);
}

// XOR-swizzled LDS layout for a 128x128 bf16 tile (linear 32KB).
// element (r,k) -> ushort index r*128 + (k ^ ((r&7)<<3)); 16B chunks stay intact.
__device__ __forceinline__ int swz(int r, int k) {
  return r * 128 + (k ^ ((r & 7) << 3));
}

union PK8 { unsigned short u[8]; uint4 q; };

#define GLDS16(g, l)                                                        \
  __builtin_amdgcn_global_load_lds(                                         \
      (const __attribute__((address_space(1))) void*)(g),                   \
      (__attribute__((address_space(3))) void*)(l), 16, 0, 0)

// Stage one 64-float half-row (f32 global -> bf16 LDS). src==nullptr -> zeros.
__device__ __forceinline__ void stage_a_half(unsigned short* Abuf, int r, int k0,
                                             const float* src) {
  #pragma unroll
  for (int j = 0; j < 8; ++j) {
    PK8 pk;
    if (src) {
      float4 v0 = *(const float4*)(src + j * 8);
      float4 v1 = *(const float4*)(src + j * 8 + 4);
      pk.u[0] = f2bf(v0.x); pk.u[1] = f2bf(v0.y);
      pk.u[2] = f2bf(v0.z); pk.u[3] = f2bf(v0.w);
      pk.u[4] = f2bf(v1.x); pk.u[5] = f2bf(v1.y);
      pk.u[6] = f2bf(v1.z); pk.u[7] = f2bf(v1.w);
    } else {
      #pragma unroll
      for (int q = 0; q < 8; ++q) pk.u[q] = 0;
    }
    *(uint4*)&Abuf[swz(r, k0 + j * 8)] = pk.q;
  }
}

// Async-copy a preconverted 32KB swizzled weight image into LDS.
// dest = wave-uniform base + lane*16 (required layout for global_load_lds).
__device__ __forceinline__ void stage_w_async(unsigned short* Wbuf,
                                              const unsigned short* img) {
  const int t = threadIdx.x;
  #pragma unroll
  for (int j = 0; j < 8; ++j) {
    const int byteoff = j * 4096 + t * 16;  // 256 thr x 16B = 4KB per j
    GLDS16((const char*)img + byteoff, (char*)Wbuf + byteoff);
  }
}

// [32 x 128] += A[32 x 128] @ B[128 x 128]; wave-tile = 2 row-tiles x 8 col-tiles.
__device__ __forceinline__ void gemm128(const unsigned short* Abuf,
                                        const unsigned short* Wbuf,
                                        int row_base, int m0, int kq,
                                        f32x4 acc[2][8]) {
  #pragma unroll
  for (int kk = 0; kk < 4; ++kk) {
    const int k0 = kk * 32 + kq * 8;
    bf16x8 a0 = *(const bf16x8*)&Abuf[swz(row_base + m0, k0)];
    bf16x8 a1 = *(const bf16x8*)&Abuf[swz(row_base + 16 + m0, k0)];
    #pragma unroll
    for (int tc = 0; tc < 8; ++tc) {
      bf16x8 b = *(const bf16x8*)&Wbuf[swz(tc * 16 + m0, k0)];
      acc[0][tc] = __builtin_amdgcn_mfma_f32_16x16x32_bf16(a0, b, acc[0][tc], 0, 0, 0);
      acc[1][tc] = __builtin_amdgcn_mfma_f32_16x16x32_bf16(a1, b, acc[1][tc], 0, 0, 0);
    }
  }
}

// C-layout: col = tc*16 + (lane&15), row = tr*16 + (lane>>4)*4 + i
__device__ __forceinline__ void write_hidden_relu(unsigned short* Abuf, f32x4 acc[2][8],
                                                  const float* __restrict__ bias,
                                                  int row_base, int m0, int kq) {
  #pragma unroll
  for (int tc = 0; tc < 8; ++tc) {
    const int col = tc * 16 + m0;
    const float b = bias[col];
    #pragma unroll
    for (int tr = 0; tr < 2; ++tr)
      #pragma unroll
      for (int i = 0; i < 4; ++i)
        Abuf[swz(row_base + tr * 16 + kq * 4 + i, col)] =
            f2bf(fmaxf(acc[tr][tc][i] + b, 0.0f));
  }
}

__device__ __forceinline__ void zero_acc(f32x4 acc[2][8]) {
  #pragma unroll
  for (int a = 0; a < 2; ++a)
    #pragma unroll
    for (int b = 0; b < 8; ++b)
      acc[a][b] = (f32x4){0.f, 0.f, 0.f, 0.f};
}

__device__ __forceinline__ void ln_stats(const f32x4 acc[2][8], float mu[2][4],
                                         float rv[2][4]) {
  #pragma unroll
  for (int tr = 0; tr < 2; ++tr) {
    float s[4] = {0, 0, 0, 0}, ss[4] = {0, 0, 0, 0};
    #pragma unroll
    for (int tc = 0; tc < 8; ++tc)
      #pragma unroll
      for (int i = 0; i < 4; ++i) {
        const float v = acc[tr][tc][i];
        s[i] += v;
        ss[i] += v * v;
      }
    #pragma unroll
    for (int off = 1; off < 16; off <<= 1) {
      #pragma unroll
      for (int i = 0; i < 4; ++i) {
        s[i] += __shfl_xor(s[i], off);
        ss[i] += __shfl_xor(ss[i], off);
      }
    }
    #pragma unroll
    for (int i = 0; i < 4; ++i) {
      const float m = s[i] * (1.0f / 128.0f);
      const float var = ss[i] * (1.0f / 128.0f) - m * m;
      mu[tr][i] = m;
      rv[tr][i] = rsqrtf(var + EPS);
    }
  }
}

// ---------------- CSR build ----------------

__global__ void hist_kernel(const int* __restrict__ ridx, unsigned* __restrict__ cnt) {
  const int e = blockIdx.x * 256 + threadIdx.x;
  if (e < N_EDGES) atomicAdd(&cnt[ridx[e]], 1u);
}

__global__ void scan1_kernel(const unsigned* __restrict__ cnt,
                             unsigned* __restrict__ offs,
                             unsigned* __restrict__ part) {
  __shared__ unsigned sh[256];
  const int t = threadIdx.x;
  const int base = blockIdx.x * 1024 + t * 4;
  unsigned v[4];
  #pragma unroll
  for (int i = 0; i < 4; ++i) v[i] = (base + i < N_NODES) ? cnt[base + i] : 0u;
  unsigned pre[4];
  pre[0] = 0; pre[1] = v[0]; pre[2] = v[0] + v[1]; pre[3] = pre[2] + v[2];
  const unsigned tot = pre[3] + v[3];
  sh[t] = tot;
  __syncthreads();
  for (int d = 1; d < 256; d <<= 1) {
    const unsigned u_ = (t >= d) ? sh[t - d] : 0u;
    __syncthreads();
    sh[t] += u_;
    __syncthreads();
  }
  const unsigned excl = sh[t] - tot;
  #pragma unroll
  for (int i = 0; i < 4; ++i)
    if (base + i < N_NODES) offs[base + i] = excl + pre[i];
  if (t == 255) part[blockIdx.x] = sh[255];
}

__global__ void scan2_kernel(unsigned* __restrict__ part, int n) {
  __shared__ unsigned sh[128];
  const int t = threadIdx.x;
  const unsigned v = (t < n) ? part[t] : 0u;
  sh[t] = v;
  __syncthreads();
  for (int d = 1; d < 128; d <<= 1) {
    const unsigned u_ = (t >= d) ? sh[t - d] : 0u;
    __syncthreads();
    sh[t] += u_;
    __syncthreads();
  }
  if (t < n) part[t] = sh[t] - v;
}

__global__ void scan3_kernel(unsigned* __restrict__ offs,
                             const unsigned* __restrict__ part,
                             unsigned* __restrict__ cursor) {
  const int i = blockIdx.x * 256 + threadIdx.x;
  if (i < N_NODES) {
    const unsigned o = offs[i] + part[i >> 10];
    offs[i] = o;
    cursor[i] = o;
  }
  if (i == 0) offs[N_NODES] = N_EDGES;
}

__global__ void scatter_kernel(const int* __restrict__ ridx,
                               unsigned* __restrict__ cursor,
                               unsigned* __restrict__ eord) {
  const int e = blockIdx.x * 256 + threadIdx.x;
  if (e < N_EDGES) {
    const unsigned p = atomicAdd(&cursor[ridx[e]], 1u);
    eord[p] = (unsigned)e;
  }
}

// ---------------- weight preconvert (9 matrices of 128x128) ----------------

struct WSrc { const float* p[9]; };

__global__ void wprep_kernel(WSrc wsrc, unsigned short* __restrict__ wimg) {
  const int id = blockIdx.x * 256 + threadIdx.x;  // 9*16384 = 147456
  const int m = id >> 14;
  const int r = id & 16383;
  const int n = r & 127;   // consecutive threads -> consecutive n (coalesced read)
  const int k = r >> 7;
  wimg[m * 16384 + swz(n, k)] = f2bf(wsrc.p[m][k * 128 + n]);
}

// ---------------- main kernels ----------------

__global__ __launch_bounds__(256, 2) void edge_kernel(
    const float* __restrict__ x, const float* __restrict__ edge_attr,
    const int* __restrict__ eidx, const unsigned short* __restrict__ wimg,
    const float* __restrict__ eb1, const float* __restrict__ eb2,
    const float* __restrict__ eb3,
    const float* __restrict__ eg, const float* __restrict__ ebeta,
    float* __restrict__ out_e, unsigned short* __restrict__ enew) {
  __shared__ unsigned short Abuf[128 * 128];
  __shared__ unsigned short Wbuf[128 * 128];

  const int t = threadIdx.x;
  const int lane = t & 63;
  const int wave = t >> 6;
  const int row_base = wave * 32;
  const int m0 = lane & 15;
  const int kq = lane >> 4;
  const long e0 = (long)blockIdx.x * 128;
  const int* sidx = eidx;
  const int* ridx = eidx + N_EDGES;

  const int sr = t >> 1;
  const int sk0 = (t & 1) * 64;
  const long se = e0 + sr;
  const bool svalid = (se < N_EDGES);

  f32x4 acc[2][8];
  zero_acc(acc);

  // ---- Layer 1: x[s]@W1a + x[r]@W1b + ea@W1c ----
  for (int p = 0; p < 3; ++p) {
    __syncthreads();
    const float* src = nullptr;
    if (svalid) {
      if (p == 0)      src = x + (long)sidx[se] * H + sk0;
      else if (p == 1) src = x + (long)ridx[se] * H + sk0;
      else             src = edge_attr + se * (long)H + sk0;
    }
    stage_a_half(Abuf, sr, sk0, src);
    stage_w_async(Wbuf, wimg + (long)p * 16384);
    __syncthreads();
    gemm128(Abuf, Wbuf, row_base, m0, kq, acc);
  }

  // ---- Layer 2 ----
  __syncthreads();
  write_hidden_relu(Abuf, acc, eb1, row_base, m0, kq);
  stage_w_async(Wbuf, wimg + 3L * 16384);
  zero_acc(acc);
  __syncthreads();
  gemm128(Abuf, Wbuf, row_base, m0, kq, acc);

  // ---- Layer 3 ----
  __syncthreads();
  write_hidden_relu(Abuf, acc, eb2, row_base, m0, kq);
  stage_w_async(Wbuf, wimg + 4L * 16384);
  zero_acc(acc);
  __syncthreads();
  gemm128(Abuf, Wbuf, row_base, m0, kq, acc);

  // ---- Epilogue: +b3, LayerNorm, residual write, e_new bf16 write ----
  float gm[8], bt[8];
  #pragma unroll
  for (int tc = 0; tc < 8; ++tc) {
    const int col = tc * 16 + m0;
    const float b3 = eb3[col];
    gm[tc] = eg[col];
    bt[tc] = ebeta[col];
    #pragma unroll
    for (int tr = 0; tr < 2; ++tr)
      #pragma unroll
      for (int i = 0; i < 4; ++i)
        acc[tr][tc][i] += b3;
  }
  float mu[2][4], rv[2][4];
  ln_stats(acc, mu, rv);

  #pragma unroll
  for (int tr = 0; tr < 2; ++tr)
    #pragma unroll
    for (int i = 0; i < 4; ++i) {
      const int row = row_base + tr * 16 + kq * 4 + i;
      const long e = e0 + row;
      if (e < N_EDGES) {
        const float m_ = mu[tr][i], r_ = rv[tr][i];
        const float* ea = edge_attr + e * (long)H;
        float* oe = out_e + e * (long)H;
        unsigned short* en = enew + e * (long)H;
        #pragma unroll
        for (int tc = 0; tc < 8; ++tc) {
          const int col = tc * 16 + m0;
          const float y = (acc[tr][tc][i] - m_) * r_ * gm[tc] + bt[tc];
          oe[col] = ea[col] + y;
          en[col] = f2bf(y);
        }
      }
    }
}

__global__ __launch_bounds__(256, 2) void node_kernel(
    const float* __restrict__ x, const unsigned short* __restrict__ enew,
    const unsigned* __restrict__ offs, const unsigned* __restrict__ eord,
    const unsigned short* __restrict__ wimg,
    const float* __restrict__ nb1, const float* __restrict__ nb2,
    const float* __restrict__ nb3,
    const float* __restrict__ ng, const float* __restrict__ nbeta,
    float* __restrict__ out_x) {
  __shared__ unsigned short Abuf[128 * 128];
  __shared__ unsigned short Wbuf[128 * 128];

  const int t = threadIdx.x;
  const int lane = t & 63;
  const int wave = t >> 6;
  const int row_base = wave * 32;
  const int m0 = lane & 15;
  const int kq = lane >> 4;
  const long n0 = (long)blockIdx.x * 128;

  const int sr = t >> 1;
  const int sk0 = (t & 1) * 64;
  const long sn = n0 + sr;
  const bool svalid = (sn < N_NODES);

  f32x4 acc[2][8];
  zero_acc(acc);

  // ---- Layer 1, part 0: x @ W1a ----
  stage_a_half(Abuf, sr, sk0, svalid ? x + sn * (long)H + sk0 : nullptr);
  stage_w_async(Wbuf, wimg + 5L * 16384);
  __syncthreads();
  gemm128(Abuf, Wbuf, row_base, m0, kq, acc);

  // ---- Layer 1, part 1: agg @ W1b  (CSR gather-sum of e_new) ----
  __syncthreads();
  {
    float av[64];
    #pragma unroll
    for (int i = 0; i < 64; ++i) av[i] = 0.f;
    if (svalid) {
      const unsigned o0 = offs[sn], o1 = offs[sn + 1];
      for (unsigned u_ = o0; u_ < o1; ++u_) {
        const unsigned short* er = enew + (long)eord[u_] * H + sk0;
        #pragma unroll
        for (int j = 0; j < 8; ++j) {
          uint4 q = *(const uint4*)(er + j * 8);
          const unsigned short* pu = (const unsigned short*)&q;
          #pragma unroll
          for (int c = 0; c < 8; ++c)
            av[j * 8 + c] += __builtin_bit_cast(float, (unsigned)pu[c] << 16);
        }
      }
    }
    #pragma unroll
    for (int j = 0; j < 8; ++j) {
      PK8 pk;
      #pragma unroll
      for (int c = 0; c < 8; ++c) pk.u[c] = f2bf(av[j * 8 + c]);
      *(uint4*)&Abuf[swz(sr, sk0 + j * 8)] = pk.q;
    }
  }
  stage_w_async(Wbuf, wimg + 6L * 16384);
  __syncthreads();
  gemm128(Abuf, Wbuf, row_base, m0, kq, acc);

  // ---- Layer 2 ----
  __syncthreads();
  write_hidden_relu(Abuf, acc, nb1, row_base, m0, kq);
  stage_w_async(Wbuf, wimg + 7L * 16384);
  zero_acc(acc);
  __syncthreads();
  gemm128(Abuf, Wbuf, row_base, m0, kq, acc);

  // ---- Layer 3 ----
  __syncthreads();
  write_hidden_relu(Abuf, acc, nb2, row_base, m0, kq);
  stage_w_async(Wbuf, wimg + 8L * 16384);
  zero_acc(acc);
  __syncthreads();
  gemm128(Abuf, Wbuf, row_base, m0, kq, acc);

  // ---- Epilogue ----
  float gm[8], bt[8];
  #pragma unroll
  for (int tc = 0; tc < 8; ++tc) {
    const int col = tc * 16 + m0;
    const float b3 = nb3[col];
    gm[tc] = ng[col];
    bt[tc] = nbeta[col];
    #pragma unroll
    for (int tr = 0; tr < 2; ++tr)
      #pragma unroll
      for (int i = 0; i < 4; ++i)
        acc[tr][tc][i] += b3;
  }
  float mu[2][4], rv[2][4];
  ln_stats(acc, mu, rv);

  #pragma unroll
  for (int tr = 0; tr < 2; ++tr)
    #pragma unroll
    for (int i = 0; i < 4; ++i) {
      const int row = row_base + tr * 16 + kq * 4 + i;
      const long n = n0 + row;
      if (n < N_NODES) {
        const float m_ = mu[tr][i], r_ = rv[tr][i];
        const float* xr = x + n * (long)H;
        float* ox = out_x + n * (long)H;
        #pragma unroll
        for (int tc = 0; tc < 8; ++tc) {
          const int col = tc * 16 + m0;
          const float y = (acc[tr][tc][i] - m_) * r_ * gm[tc] + bt[tc];
          ox[col] = xr[col] + y;
        }
      }
    }
}

extern "C" void kernel_launch(void* const* d_in, const int* in_sizes, int n_in,
                              void* d_out, int out_size, void* d_ws, size_t ws_size,
                              hipStream_t stream) {
  (void)in_sizes; (void)n_in; (void)out_size; (void)ws_size;
  const float* x         = (const float*)d_in[0];
  const float* edge_attr = (const float*)d_in[1];
  const int*   eidx      = (const int*)d_in[2];
  const float* eW1 = (const float*)d_in[3];
  const float* eb1 = (const float*)d_in[4];
  const float* eW2 = (const float*)d_in[5];
  const float* eb2 = (const float*)d_in[6];
  const float* eW3 = (const float*)d_in[7];
  const float* eb3 = (const float*)d_in[8];
  const float* eg  = (const float*)d_in[9];
  const float* ebt = (const float*)d_in[10];
  const float* nW1 = (const float*)d_in[11];
  const float* nb1 = (const float*)d_in[12];
  const float* nW2 = (const float*)d_in[13];
  const float* nb2 = (const float*)d_in[14];
  const float* nW3 = (const float*)d_in[15];
  const float* nb3 = (const float*)d_in[16];
  const float* ng  = (const float*)d_in[17];
  const float* nbt = (const float*)d_in[18];

  float* out_x = (float*)d_out;                        // N_NODES*H
  float* out_e = (float*)d_out + (size_t)N_NODES * H;  // N_EDGES*H

  // ws layout (bytes)
  char* w = (char*)d_ws;
  unsigned short* enew = (unsigned short*)(w + 0);            // 128,000,000
  unsigned short* wimg = (unsigned short*)(w + 128000000);    //    294,912 (9*32KB)
  unsigned* offs   = (unsigned*)(w + 128327680);              //    400,128
  unsigned* cnt    = (unsigned*)(w + 128727808);              //    400,128
  unsigned* cursor = (unsigned*)(w + 129127936);              //    400,128
  unsigned* part   = (unsigned*)(w + 129528064);              //      1,024
  unsigned* eord   = (unsigned*)(w + 129529088);              //  2,000,000
  // total ~131.6 MB

  const int* ridx = eidx + N_EDGES;

  hipMemsetAsync(cnt, 0, (size_t)N_NODES * sizeof(unsigned), stream);

  WSrc wsrc;
  wsrc.p[0] = eW1;
  wsrc.p[1] = eW1 + 16384;
  wsrc.p[2] = eW1 + 32768;
  wsrc.p[3] = eW2;
  wsrc.p[4] = eW3;
  wsrc.p[5] = nW1;
  wsrc.p[6] = nW1 + 16384;
  wsrc.p[7] = nW2;
  wsrc.p[8] = nW3;
  wprep_kernel<<<576, 256, 0, stream>>>(wsrc, wimg);

  hist_kernel<<<(N_EDGES + 255) / 256, 256, 0, stream>>>(ridx, cnt);
  scan1_kernel<<<(N_NODES + 1023) / 1024, 256, 0, stream>>>(cnt, offs, part);
  scan2_kernel<<<1, 128, 0, stream>>>(part, (N_NODES + 1023) / 1024);
  scan3_kernel<<<(N_NODES + 255) / 256, 256, 0, stream>>>(offs, part, cursor);
  scatter_kernel<<<(N_EDGES + 255) / 256, 256, 0, stream>>>(ridx, cursor, eord);

  const int eblocks = (N_EDGES + 127) / 128;  // 3907
  const int nblocks = (N_NODES + 127) / 128;  // 782
  edge_kernel<<<eblocks, 256, 0, stream>>>(x, edge_attr, eidx, wimg, eb1, eb2, eb3,
                                           eg, ebt, out_e, enew);
  node_kernel<<<nblocks, 256, 0, stream>>>(x, enew, offs, eord, wimg, nb1, nb2, nb3,
                                           ng, nbt, out_x);
}